// Round 18
// baseline (6045.445 us; speedup 1.0000x reference)
//
#include <hip/hip_runtime.h>
#include <hip/hip_bf16.h>

using bf16 = __hip_bfloat16;
typedef __attribute__((ext_vector_type(8))) short bf16x8;   // 8 bf16 = 4 VGPRs (MFMA A/B frag)
typedef __attribute__((ext_vector_type(4))) float f32x4;    // MFMA C/D frag

__device__ __forceinline__ float b2f(unsigned short u) {
  union { unsigned int i; float f; } x; x.i = ((unsigned int)u) << 16; return x.f;
}
__device__ __forceinline__ unsigned short f2b(float f) {
  __hip_bfloat16 h = __float2bfloat16(f);
  return *reinterpret_cast<unsigned short*>(&h);
}

__device__ __forceinline__ void load16_to_lds(const bf16* g, void* lds) {
  __builtin_amdgcn_global_load_lds((const __attribute__((address_space(1))) void*)g,
                                   (__attribute__((address_space(3))) void*)lds, 16, 0, 0);
}

#define FENCE() asm volatile("" ::: "memory")
#define BAR() do { FENCE(); __builtin_amdgcn_s_barrier(); FENCE(); } while (0)
#define SCHED_PIN() __builtin_amdgcn_sched_barrier(0)

// ---------------- elementwise cast f32 -> bf16 ----------------
__global__ void cast_f32_bf16(const float* __restrict__ in, bf16* __restrict__ out, size_t n) {
  size_t i0 = ((size_t)blockIdx.x * 256 + threadIdx.x) * 4;
  size_t stride = (size_t)gridDim.x * 256 * 4;
  for (size_t i = i0; i < n; i += stride) {
    float4 f = *(const float4*)(in + i);
    ushort4 o;
    o.x = f2b(f.x); o.y = f2b(f.y); o.z = f2b(f.z); o.w = f2b(f.w);
    *(ushort4*)(out + i) = o;
  }
}

// ---------------- transpose + cast: in [R][C] f32 -> out [C][R] bf16 ----------------
__global__ void transpose_cast(const float* __restrict__ in, bf16* __restrict__ out, int R, int C) {
  __shared__ float tile[32][33];
  int tx = threadIdx.x & 31, ty = threadIdx.x >> 5;  // 32 x 8
  int r0 = blockIdx.y * 32, c0 = blockIdx.x * 32;
  #pragma unroll
  for (int i = 0; i < 32; i += 8)
    tile[ty + i][tx] = in[(size_t)(r0 + ty + i) * C + (c0 + tx)];
  __syncthreads();
  #pragma unroll
  for (int i = 0; i < 32; i += 8)
    out[(size_t)(c0 + ty + i) * R + (r0 + tx)] = __float2bfloat16(tile[tx][ty + i]);
}

// ============ 256x256 8-phase GEMM (T2+T3+T4+T5 + sched-pin): C = A[M,K]*B^T ============
// B stored [N][K] row-major. BK=64, 512 threads = 8 waves (2M x 4N), LDS 128KB 2-buf.
// EPI 0: out = elu(acc + bias[n]);  EPI 2: out = acc * e(Ea[m,n]), e = a>0?1:a+1
template<int EPI>
__global__ __launch_bounds__(512, 2)
void gemm256(const bf16* __restrict__ A, const bf16* __restrict__ Bm,
             int M, int N, int K,
             bf16* __restrict__ OutB,
             const float* __restrict__ bias,
             const bf16* __restrict__ Ea) {
  __shared__ __align__(16) char pool[131072];
  char* Albs = pool;           // A tiles [2buf][256 rows][128B], XOR-swizzled
  char* Blbs = pool + 65536;   // B tiles, same layout
  const int tid = threadIdx.x;
  const int l = tid & 63, w = tid >> 6;
  const int lane16 = l & 15, lh = l >> 4;
  const int wr = w >> 2, wc = w & 3;            // wave grid 2(M) x 4(N)
  const int bm0 = blockIdx.y * 256, bn0 = blockIdx.x * 256;
  const int NT2 = K >> 7;

  auto stage = [&](const bf16* G, int grow0, int kbase, char* ldsbase) {
    #pragma unroll
    for (int r = 0; r < 2; ++r) {
      int p = (r * 512 + tid) * 16;
      int row = p >> 7, colb = p & 127;
      int cs = colb ^ ((row & 7) << 4);
      const bf16* g = G + (size_t)(grow0 + row) * K + kbase + (cs >> 1);
      load16_to_lds(g, ldsbase + (size_t)(r * 512 + w * 64) * 16);  // wave-uniform base
    }
  };
  auto rd = [&](const char* base, int row, int colb) -> bf16x8 {
    return *(const bf16x8*)(base + row * 128 + (colb ^ ((row & 7) << 4)));
  };

  f32x4 acc[8][4] = {};
  bf16x8 a_r[4][2], b_r[4][2];

  #define RD_A(mq, buf) { _Pragma("unroll") for (int i = 0; i < 4; ++i) \
      _Pragma("unroll") for (int kk = 0; kk < 2; ++kk) \
      a_r[i][kk] = rd(Albs + (buf) * 32768, wr * 128 + (mq) * 64 + i * 16 + lane16, kk * 64 + lh * 16); }
  #define RD_B(buf) { _Pragma("unroll") for (int nf = 0; nf < 4; ++nf) \
      _Pragma("unroll") for (int kk = 0; kk < 2; ++kk) \
      b_r[nf][kk] = rd(Blbs + (buf) * 32768, wc * 64 + nf * 16 + lane16, kk * 64 + lh * 16); }
  #define MFMA_H(mq, n0) { __builtin_amdgcn_s_setprio(1); \
      _Pragma("unroll") for (int i = 0; i < 4; ++i) \
      _Pragma("unroll") for (int nn = 0; nn < 2; ++nn) \
      _Pragma("unroll") for (int kk = 0; kk < 2; ++kk) \
        acc[(mq)*4+i][(n0)+nn] = __builtin_amdgcn_mfma_f32_16x16x32_bf16( \
            a_r[i][kk], b_r[(n0)+nn][kk], acc[(mq)*4+i][(n0)+nn], 0, 0, 0); \
      __builtin_amdgcn_s_setprio(0); }
  #define PHASE(BODY_PRE, MFMA_CALL) { BODY_PRE; BAR(); SCHED_PIN(); MFMA_CALL; SCHED_PIN(); BAR(); }

  // prologue: buf0 {B0,B1,A0,A1} (ktile 0); buf1 {B0,B1,A0} (ktile 1). 7 halves = 14 loads.
  stage(Bm, bn0 + 0,   0,  Blbs + 0);
  stage(Bm, bn0 + 128, 0,  Blbs + 16384);
  stage(A,  bm0 + 0,   0,  Albs + 0);
  stage(A,  bm0 + 128, 0,  Albs + 16384);
  stage(Bm, bn0 + 0,   64, Blbs + 32768);
  stage(Bm, bn0 + 128, 64, Blbs + 32768 + 16384);
  stage(A,  bm0 + 0,   64, Albs + 32768);
  asm volatile("s_waitcnt vmcnt(6)" ::: "memory");  // buf0's 4 halves landed
  SCHED_PIN();
  BAR();

  for (int t = 0; t < NT2; ++t) {
    const int k2 = (2 * t + 2) * 64, k3 = (2 * t + 3) * 64;
    const bool nl = (t < NT2 - 1);
    PHASE({ RD_B(0); RD_A(0, 0); stage(A, bm0 + 128, (2 * t + 1) * 64, Albs + 32768 + 16384); },
          MFMA_H(0, 0));
    PHASE({ if (nl) stage(Bm, bn0 + 0, k2, Blbs + 0); }, MFMA_H(0, 2));
    PHASE({ RD_A(1, 0); if (nl) stage(Bm, bn0 + 128, k2, Blbs + 16384); }, MFMA_H(1, 0));
    { if (nl) stage(A, bm0 + 0, k2, Albs + 0);
      BAR(); SCHED_PIN(); MFMA_H(1, 2); SCHED_PIN();
      if (nl) { asm volatile("s_waitcnt vmcnt(6)" ::: "memory"); }
      else    { asm volatile("s_waitcnt vmcnt(0)" ::: "memory"); }
      SCHED_PIN(); BAR(); }
    PHASE({ RD_B(1); RD_A(0, 1); if (nl) stage(A, bm0 + 128, k2, Albs + 16384); },
          MFMA_H(0, 0));
    PHASE({ if (nl) stage(Bm, bn0 + 0, k3, Blbs + 32768); }, MFMA_H(0, 2));
    PHASE({ RD_A(1, 1); if (nl) stage(Bm, bn0 + 128, k3, Blbs + 32768 + 16384); }, MFMA_H(1, 0));
    { if (nl) stage(A, bm0 + 0, k3, Albs + 32768);
      BAR(); SCHED_PIN(); MFMA_H(1, 2); SCHED_PIN();
      if (nl) { asm volatile("s_waitcnt vmcnt(6)" ::: "memory"); }
      SCHED_PIN(); BAR(); }
  }

  // ---- epilogue: per-wave repack (scratch aliases dead pool), 16B bf16x8 stores
  float* scr = (float*)(pool + w * 4352);   // per-wave 16x68 f32
  const int row0 = bm0 + wr * 128, col0 = bn0 + wc * 64;
  const int erow = l >> 3, ecol = (l & 7) * 8;
  f32x4 bias0 = {}, bias1 = {};
  bf16x8 ea_pre[8][2];
  if (EPI == 0) {
    bias0 = *(const f32x4*)&bias[col0 + ecol];
    bias1 = *(const f32x4*)&bias[col0 + ecol + 4];
  } else {
    #pragma unroll
    for (int mf = 0; mf < 8; ++mf)
      #pragma unroll
      for (int p = 0; p < 2; ++p) {
        int gm = row0 + mf * 16 + p * 8 + erow;
        ea_pre[mf][p] = *(const bf16x8*)&Ea[(size_t)gm * N + col0 + ecol];
      }
  }
  SCHED_PIN();
  #pragma unroll
  for (int mf = 0; mf < 8; ++mf) {
    #pragma unroll
    for (int nf = 0; nf < 4; ++nf)
      #pragma unroll
      for (int q = 0; q < 4; ++q)
        scr[(lh * 4 + q) * 68 + nf * 16 + lane16] = acc[mf][nf][q];
    #pragma unroll
    for (int p = 0; p < 2; ++p) {
      int row = p * 8 + erow;
      const float* sp = &scr[row * 68 + ecol];
      f32x4 lo = *(const f32x4*)sp;
      f32x4 hi = *(const f32x4*)(sp + 4);
      int gm = row0 + mf * 16 + row;
      size_t idx = (size_t)gm * N + col0 + ecol;
      bf16x8 ov;
      if (EPI == 0) {
        #pragma unroll
        for (int j = 0; j < 8; ++j) {
          float fj = (j < 4) ? lo[j] : hi[j - 4];
          float bj = (j < 4) ? bias0[j] : bias1[j - 4];
          float hv = fj + bj;
          float a = hv > 0.f ? hv : expm1f(hv);
          ov[j] = (short)f2b(a);
        }
      } else {
        bf16x8 ea = ea_pre[mf][p];
        #pragma unroll
        for (int j = 0; j < 8; ++j) {
          float fj = (j < 4) ? lo[j] : hi[j - 4];
          float a = b2f((unsigned short)ea[j]);
          float e = a > 0.f ? 1.f : a + 1.f;   // elu'(h) from a=elu(h)
          ov[j] = (short)f2b(fj * e);
        }
      }
      *(bf16x8*)(&OutB[idx]) = ov;
    }
  }
  #undef RD_A
  #undef RD_B
  #undef MFMA_H
  #undef PHASE
}

// ---------------- 64x128 GEMM (R18: 2x grid for latency hiding) ----------------
// Grid = dim3(M/64, N/128): 1024 blocks = 4/CU (was 512 = 2/CU, grid-limited 22% occ).
// XCD = row-block % 8 preserved (gridDim.x=128 divisible by 8) -> A panels L2-local.
// 4 waves, wave-tile 64x32 (wave w covers cols w*32..w*32+31). T2 XOR swizzle kept.
// EPI 1: out_f32 = acc + bias[n] + Xadd[m,n]  (GEMM2)
// EPI 3 (GEMM4): out_bf16 = acc (skip if null) + fused Hutchinson partials into
//   sdg[(blockIdx.y*4 + w)*M + row] (unique slot per wave -> no race, deterministic).
template<int EPI>
__global__ __launch_bounds__(256)
void gemm_bt(const bf16* __restrict__ A, const bf16* __restrict__ Bm,
             int M, int N, int K,
             bf16* __restrict__ OutB, float* __restrict__ OutF,
             const float* __restrict__ bias, const float* __restrict__ Xadd,
             const float* __restrict__ Vf, float* __restrict__ sdg, float coef) {
  __shared__ __align__(16) char pool[4 * 4352];   // As 4KB + Bs 8KB; epi scratch aliases
  bf16* As = (bf16*)pool;                  // [64][32]
  bf16* Bs = (bf16*)(pool + 4096);         // [128][32]
  const int tid = threadIdx.x;
  const int l = tid & 63, w = tid >> 6;    // 4 waves, wave = N-slice
  const int lane16 = l & 15, lh = l >> 4;
  const int bm0 = blockIdx.x * 64, bn0 = blockIdx.y * 128;   // x = ROW block (XCD-local)

  f32x4 acc[4][2] = {};
  const int nk = K >> 5;
  for (int kt = 0; kt < nk; ++kt) {
    const size_t kbase = (size_t)kt * 32;
    // A tile: 64x32 = 4KB = 1 load/thread; B tile: 128x32 = 8KB = 2 loads
    {
      int c = w * 64 + l;                  // 0..255
      int row = c >> 2;                    // 0..63
      int cbs = ((((c & 3) << 4) ^ ((row & 6) << 3)) >> 1);   // inverse-swizzled src
      const bf16* ga = A + (size_t)(bm0 + row) * K + kbase + cbs;
      load16_to_lds(ga, (char*)As + (size_t)(w * 64) * 16);
    }
    #pragma unroll
    for (int i = 0; i < 2; ++i) {
      int c = i * 256 + w * 64 + l;
      int row = c >> 2;                    // 0..127
      int cbs = ((((c & 3) << 4) ^ ((row & 6) << 3)) >> 1);
      const bf16* gb = Bm + (size_t)(bn0 + row) * K + kbase + cbs;
      load16_to_lds(gb, (char*)Bs + (size_t)(i * 256 + w * 64) * 16);
    }
    __syncthreads();
    bf16x8 af[4], bfv[2];
    #pragma unroll
    for (int r = 0; r < 4; ++r) {
      int arow = r * 16 + lane16;
      int aoff = (lh << 4) ^ ((arow & 6) << 3);
      af[r] = *(const bf16x8*)((const char*)As + arow * 64 + aoff);
    }
    #pragma unroll
    for (int c2 = 0; c2 < 2; ++c2) {
      int brow = w * 32 + c2 * 16 + lane16;
      int boff = (lh << 4) ^ ((brow & 6) << 3);
      bfv[c2] = *(const bf16x8*)((const char*)Bs + brow * 64 + boff);
    }
    #pragma unroll
    for (int r = 0; r < 4; ++r)
      #pragma unroll
      for (int c2 = 0; c2 < 2; ++c2)
        acc[r][c2] = __builtin_amdgcn_mfma_f32_16x16x32_bf16(af[r], bfv[c2], acc[r][c2], 0, 0, 0);
    __syncthreads();
  }

  if (EPI == 1) {
    #pragma unroll
    for (int r = 0; r < 4; ++r) {
      int gm_base = bm0 + r * 16 + lh * 4;
      #pragma unroll
      for (int c2 = 0; c2 < 2; ++c2) {
        int gn = bn0 + w * 32 + c2 * 16 + lane16;
        #pragma unroll
        for (int q = 0; q < 4; ++q) {
          size_t idx = (size_t)(gm_base + q) * N + gn;
          OutF[idx] = acc[r][c2][q] + bias[gn] + Xadd[idx];
        }
      }
    }
  } else {
    float* scr = (float*)(pool + w * 4352);   // per-wave 16x36 f32 (private)
    float* sdgslot = sdg + (size_t)(blockIdx.y * 4 + w) * M;
    #pragma unroll
    for (int mf = 0; mf < 4; ++mf) {
      #pragma unroll
      for (int c2 = 0; c2 < 2; ++c2)
        #pragma unroll
        for (int q = 0; q < 4; ++q)
          scr[(lh * 4 + q) * 36 + c2 * 16 + lane16] = acc[mf][c2][q];
      // per-wave private scratch: same-wave LDS RAW is program-ordered (lgkmcnt)
      {
        int row = l >> 2;                 // 0..15
        int c0 = (l & 3) * 8;             // 0..24
        const float* sp = &scr[row * 36 + c0];
        f32x4 lo = *(const f32x4*)sp;
        f32x4 hi = *(const f32x4*)(sp + 4);
        int gm = bm0 + mf * 16 + row;
        int gn = bn0 + w * 32 + c0;
        size_t idx = (size_t)gm * N + gn;
        // fused Hutchinson partial over this wave's 32 cols
        f32x4 v0 = *(const f32x4*)(Vf + idx);
        f32x4 v1 = *(const f32x4*)(Vf + idx + 4);
        float s = lo[0]*v0[0] + lo[1]*v0[1] + lo[2]*v0[2] + lo[3]*v0[3]
                + hi[0]*v1[0] + hi[1]*v1[1] + hi[2]*v1[2] + hi[3]*v1[3];
        s += __shfl_xor(s, 1); s += __shfl_xor(s, 2);
        if ((l & 3) == 0) sdgslot[gm] += coef * s;   // unique (slot,row) per wave
        if (OutB) {
          bf16x8 ov;
          #pragma unroll
          for (int j = 0; j < 8; ++j) {
            float fj = (j < 4) ? lo[j] : hi[j - 4];
            ov[j] = (short)f2b(fj);
          }
          *(bf16x8*)(&OutB[idx]) = ov;
        }
      }
      FENCE();
    }
  }
}

// ---------------- finalize: out[b] = ldz[b] + mean_s (sum_p sdgpart[s][p][b]) ----------------
__global__ void finalize(const float* __restrict__ ldz, const float* __restrict__ sdp,
                         float* __restrict__ out, int B, int S) {
  int b = blockIdx.x * 256 + threadIdx.x;
  if (b >= B) return;
  float acc = 0.f;
  for (int s = 0; s < S; ++s)
    for (int p = 0; p < 32; ++p)
      acc += sdp[((size_t)s * 32 + p) * B + b];
  out[b] = ldz[b] + acc / (float)S;
}

extern "C" void kernel_launch(void* const* d_in, const int* in_sizes, int n_in,
                              void* d_out, int out_size, void* d_ws, size_t ws_size,
                              hipStream_t stream) {
  const int B = 8192, D = 1024, H = 4096, S = 4, NPS = 8;
  const float* x   = (const float*)d_in[0];
  const float* ldz = (const float*)d_in[1];
  const float* W1  = (const float*)d_in[2];
  const float* b1  = (const float*)d_in[3];
  const float* W2  = (const float*)d_in[4];
  const float* b2  = (const float*)d_in[5];
  const float* v   = (const float*)d_in[6];
  float* z_out  = (float*)d_out;
  float* ld_out = z_out + (size_t)B * D;

  char* ws = (char*)d_ws;
  size_t off = 0;
  auto alloc = [&](size_t bytes) {
    char* p = ws + off; off = (off + bytes + 255) & ~(size_t)255; return p;
  };
  // Workspace ~164 MB (R16 proved >=240 MB usable)
  float* sdgpart = (float*)alloc((size_t)S * 32 * B * 4);     // 4 MB partial dots
  bf16* W1b  = (bf16*)alloc((size_t)D * H * 2);               // 8 MB  (B for GEMM4)
  bf16* W2b  = (bf16*)alloc((size_t)D * H * 2);               // 8 MB  (B for GEMM3)
  bf16* abuf = (bf16*)alloc((size_t)B * H * 2);               // 64 MB (a = elu(h))
  bf16* wreg = (bf16*)alloc((size_t)B * D * 2);               // 16 MB (w state)
  bf16* treg = (bf16*)alloc((size_t)B * H * 2);               // 64 MB (t)
  // forward-only buffers alias INTO treg (dead before power series overwrites it):
  bf16* xb  = treg;                                            // 16 MB (x cast)
  bf16* W1T = (bf16*)((char*)treg + (size_t)16 * 1024 * 1024); // 8 MB
  bf16* W2T = (bf16*)((char*)treg + (size_t)24 * 1024 * 1024); // 8 MB
  (void)ws_size; (void)in_sizes; (void)n_in; (void)out_size;

  hipMemsetAsync(sdgpart, 0, (size_t)S * 32 * B * 4, stream);

  cast_f32_bf16<<<1024, 256, 0, stream>>>(x,  xb,  (size_t)B * D);
  cast_f32_bf16<<<1024, 256, 0, stream>>>(W1, W1b, (size_t)D * H);
  cast_f32_bf16<<<1024, 256, 0, stream>>>(W2, W2b, (size_t)D * H);
  transpose_cast<<<dim3(H / 32, D / 32), 256, 0, stream>>>(W1, W1T, D, H);
  transpose_cast<<<dim3(D / 32, H / 32), 256, 0, stream>>>(W2, W2T, H, D);

  // forward: a = elu(x@W1 + b1);  z = x + a@W2 + b2
  gemm256<0><<<dim3(H / 256, B / 256), 512, 0, stream>>>(xb, W1T, B, H, D,
      abuf, b1, nullptr);
  gemm_bt<1><<<dim3(B / 64, D / 128), 256, 0, stream>>>(abuf, W2T, B, D, H,
      nullptr, z_out, b2, x, nullptr, nullptr, 0.f);

  // power series, one sample at a time:
  //   t = (w@W2^T).*e ;  w <- t@W1^T with FUSED <w,v> partial accumulation
  for (int s = 0; s < S; ++s) {
    const float* vs = v + (size_t)s * B * D;
    cast_f32_bf16<<<1024, 256, 0, stream>>>(vs, wreg, (size_t)B * D);  // w_0 = v_s
    for (int k = 1; k <= NPS; ++k) {
      gemm256<2><<<dim3(H / 256, B / 256), 512, 0, stream>>>(wreg, W2b, B, H, D,
          treg, nullptr, abuf);
      float coef = ((k & 1) ? 1.f : -1.f) / (float)k;
      bf16* wout = (k < NPS) ? wreg : nullptr;   // last step's w never read again
      gemm_bt<3><<<dim3(B / 64, D / 128), 256, 0, stream>>>(treg, W1b, B, D, H,
          wout, nullptr, nullptr, nullptr, vs, sdgpart + (size_t)s * 32 * B, coef);
    }
  }
  finalize<<<B / 256, 256, 0, stream>>>(ldz, sdgpart, ld_out, B, S);
}

// Round 19
// 5822.573 us; speedup vs baseline: 1.0383x; 1.0383x over previous
//
#include <hip/hip_runtime.h>
#include <hip/hip_bf16.h>

using bf16 = __hip_bfloat16;
typedef __attribute__((ext_vector_type(8))) short bf16x8;   // 8 bf16 = 4 VGPRs (MFMA A/B frag)
typedef __attribute__((ext_vector_type(4))) float f32x4;    // MFMA C/D frag
typedef __attribute__((ext_vector_type(8))) unsigned char uchar8;

__device__ __forceinline__ float b2f(unsigned short u) {
  union { unsigned int i; float f; } x; x.i = ((unsigned int)u) << 16; return x.f;
}
__device__ __forceinline__ unsigned short f2b(float f) {
  __hip_bfloat16 h = __float2bfloat16(f);
  return *reinterpret_cast<unsigned short*>(&h);
}

__device__ __forceinline__ void load16_to_lds(const bf16* g, void* lds) {
  __builtin_amdgcn_global_load_lds((const __attribute__((address_space(1))) void*)g,
                                   (__attribute__((address_space(3))) void*)lds, 16, 0, 0);
}

#define FENCE() asm volatile("" ::: "memory")
#define BAR() do { FENCE(); __builtin_amdgcn_s_barrier(); FENCE(); } while (0)
#define SCHED_PIN() __builtin_amdgcn_sched_barrier(0)

// ---------------- elementwise cast f32 -> bf16 ----------------
__global__ void cast_f32_bf16(const float* __restrict__ in, bf16* __restrict__ out, size_t n) {
  size_t i0 = ((size_t)blockIdx.x * 256 + threadIdx.x) * 4;
  size_t stride = (size_t)gridDim.x * 256 * 4;
  for (size_t i = i0; i < n; i += stride) {
    float4 f = *(const float4*)(in + i);
    ushort4 o;
    o.x = f2b(f.x); o.y = f2b(f.y); o.z = f2b(f.z); o.w = f2b(f.w);
    *(ushort4*)(out + i) = o;
  }
}

// ---------------- transpose + cast: in [R][C] f32 -> out [C][R] bf16 ----------------
__global__ void transpose_cast(const float* __restrict__ in, bf16* __restrict__ out, int R, int C) {
  __shared__ float tile[32][33];
  int tx = threadIdx.x & 31, ty = threadIdx.x >> 5;  // 32 x 8
  int r0 = blockIdx.y * 32, c0 = blockIdx.x * 32;
  #pragma unroll
  for (int i = 0; i < 32; i += 8)
    tile[ty + i][tx] = in[(size_t)(r0 + ty + i) * C + (c0 + tx)];
  __syncthreads();
  #pragma unroll
  for (int i = 0; i < 32; i += 8)
    out[(size_t)(c0 + ty + i) * R + (r0 + tx)] = __float2bfloat16(tile[tx][ty + i]);
}

// ============ 256x256 8-phase GEMM (T2+T3+T4+T5 + sched-pin): C = A[M,K]*B^T ============
// B stored [N][K] row-major. BK=64, 512 threads = 8 waves (2M x 4N), LDS 128KB 2-buf.
// EPI 0: out = elu(acc + bias[n]); ALSO store e=elu'(h) quantized u8 to Eout (for GEMM3)
// EPI 2: out = acc * e, e = Ea_u8[m,n] / 255   (u8 halves the Ea stream: 64->32 MB)
template<int EPI>
__global__ __launch_bounds__(512, 2)
void gemm256(const bf16* __restrict__ A, const bf16* __restrict__ Bm,
             int M, int N, int K,
             bf16* __restrict__ OutB,
             const float* __restrict__ bias,
             const unsigned char* __restrict__ Ea,
             unsigned char* __restrict__ Eout) {
  __shared__ __align__(16) char pool[131072];
  char* Albs = pool;           // A tiles [2buf][256 rows][128B], XOR-swizzled
  char* Blbs = pool + 65536;   // B tiles, same layout
  const int tid = threadIdx.x;
  const int l = tid & 63, w = tid >> 6;
  const int lane16 = l & 15, lh = l >> 4;
  const int wr = w >> 2, wc = w & 3;            // wave grid 2(M) x 4(N)
  const int bm0 = blockIdx.y * 256, bn0 = blockIdx.x * 256;
  const int NT2 = K >> 7;

  auto stage = [&](const bf16* G, int grow0, int kbase, char* ldsbase) {
    #pragma unroll
    for (int r = 0; r < 2; ++r) {
      int p = (r * 512 + tid) * 16;
      int row = p >> 7, colb = p & 127;
      int cs = colb ^ ((row & 7) << 4);
      const bf16* g = G + (size_t)(grow0 + row) * K + kbase + (cs >> 1);
      load16_to_lds(g, ldsbase + (size_t)(r * 512 + w * 64) * 16);  // wave-uniform base
    }
  };
  auto rd = [&](const char* base, int row, int colb) -> bf16x8 {
    return *(const bf16x8*)(base + row * 128 + (colb ^ ((row & 7) << 4)));
  };

  f32x4 acc[8][4] = {};
  bf16x8 a_r[4][2], b_r[4][2];

  #define RD_A(mq, buf) { _Pragma("unroll") for (int i = 0; i < 4; ++i) \
      _Pragma("unroll") for (int kk = 0; kk < 2; ++kk) \
      a_r[i][kk] = rd(Albs + (buf) * 32768, wr * 128 + (mq) * 64 + i * 16 + lane16, kk * 64 + lh * 16); }
  #define RD_B(buf) { _Pragma("unroll") for (int nf = 0; nf < 4; ++nf) \
      _Pragma("unroll") for (int kk = 0; kk < 2; ++kk) \
      b_r[nf][kk] = rd(Blbs + (buf) * 32768, wc * 64 + nf * 16 + lane16, kk * 64 + lh * 16); }
  #define MFMA_H(mq, n0) { __builtin_amdgcn_s_setprio(1); \
      _Pragma("unroll") for (int i = 0; i < 4; ++i) \
      _Pragma("unroll") for (int nn = 0; nn < 2; ++nn) \
      _Pragma("unroll") for (int kk = 0; kk < 2; ++kk) \
        acc[(mq)*4+i][(n0)+nn] = __builtin_amdgcn_mfma_f32_16x16x32_bf16( \
            a_r[i][kk], b_r[(n0)+nn][kk], acc[(mq)*4+i][(n0)+nn], 0, 0, 0); \
      __builtin_amdgcn_s_setprio(0); }
  #define PHASE(BODY_PRE, MFMA_CALL) { BODY_PRE; BAR(); SCHED_PIN(); MFMA_CALL; SCHED_PIN(); BAR(); }

  // prologue: buf0 {B0,B1,A0,A1} (ktile 0); buf1 {B0,B1,A0} (ktile 1). 7 halves = 14 loads.
  stage(Bm, bn0 + 0,   0,  Blbs + 0);
  stage(Bm, bn0 + 128, 0,  Blbs + 16384);
  stage(A,  bm0 + 0,   0,  Albs + 0);
  stage(A,  bm0 + 128, 0,  Albs + 16384);
  stage(Bm, bn0 + 0,   64, Blbs + 32768);
  stage(Bm, bn0 + 128, 64, Blbs + 32768 + 16384);
  stage(A,  bm0 + 0,   64, Albs + 32768);
  asm volatile("s_waitcnt vmcnt(6)" ::: "memory");  // buf0's 4 halves landed
  SCHED_PIN();
  BAR();

  for (int t = 0; t < NT2; ++t) {
    const int k2 = (2 * t + 2) * 64, k3 = (2 * t + 3) * 64;
    const bool nl = (t < NT2 - 1);
    PHASE({ RD_B(0); RD_A(0, 0); stage(A, bm0 + 128, (2 * t + 1) * 64, Albs + 32768 + 16384); },
          MFMA_H(0, 0));
    PHASE({ if (nl) stage(Bm, bn0 + 0, k2, Blbs + 0); }, MFMA_H(0, 2));
    PHASE({ RD_A(1, 0); if (nl) stage(Bm, bn0 + 128, k2, Blbs + 16384); }, MFMA_H(1, 0));
    { if (nl) stage(A, bm0 + 0, k2, Albs + 0);
      BAR(); SCHED_PIN(); MFMA_H(1, 2); SCHED_PIN();
      if (nl) { asm volatile("s_waitcnt vmcnt(6)" ::: "memory"); }
      else    { asm volatile("s_waitcnt vmcnt(0)" ::: "memory"); }
      SCHED_PIN(); BAR(); }
    PHASE({ RD_B(1); RD_A(0, 1); if (nl) stage(A, bm0 + 128, k2, Albs + 16384); },
          MFMA_H(0, 0));
    PHASE({ if (nl) stage(Bm, bn0 + 0, k3, Blbs + 32768); }, MFMA_H(0, 2));
    PHASE({ RD_A(1, 1); if (nl) stage(Bm, bn0 + 128, k3, Blbs + 32768 + 16384); }, MFMA_H(1, 0));
    { if (nl) stage(A, bm0 + 0, k3, Albs + 32768);
      BAR(); SCHED_PIN(); MFMA_H(1, 2); SCHED_PIN();
      if (nl) { asm volatile("s_waitcnt vmcnt(6)" ::: "memory"); }
      SCHED_PIN(); BAR(); }
  }

  // ---- epilogue: per-wave repack (scratch aliases dead pool), 16B bf16x8 stores
  float* scr = (float*)(pool + w * 4352);   // per-wave 16x68 f32
  const int row0 = bm0 + wr * 128, col0 = bn0 + wc * 64;
  const int erow = l >> 3, ecol = (l & 7) * 8;
  f32x4 bias0 = {}, bias1 = {};
  uchar8 ea_pre[8][2];
  if (EPI == 0) {
    bias0 = *(const f32x4*)&bias[col0 + ecol];
    bias1 = *(const f32x4*)&bias[col0 + ecol + 4];
  } else {
    #pragma unroll
    for (int mf = 0; mf < 8; ++mf)
      #pragma unroll
      for (int p = 0; p < 2; ++p) {
        int gm = row0 + mf * 16 + p * 8 + erow;
        ea_pre[mf][p] = *(const uchar8*)&Ea[(size_t)gm * N + col0 + ecol];
      }
  }
  SCHED_PIN();
  #pragma unroll
  for (int mf = 0; mf < 8; ++mf) {
    #pragma unroll
    for (int nf = 0; nf < 4; ++nf)
      #pragma unroll
      for (int q = 0; q < 4; ++q)
        scr[(lh * 4 + q) * 68 + nf * 16 + lane16] = acc[mf][nf][q];
    #pragma unroll
    for (int p = 0; p < 2; ++p) {
      int row = p * 8 + erow;
      const float* sp = &scr[row * 68 + ecol];
      f32x4 lo = *(const f32x4*)sp;
      f32x4 hi = *(const f32x4*)(sp + 4);
      int gm = row0 + mf * 16 + row;
      size_t idx = (size_t)gm * N + col0 + ecol;
      bf16x8 ov;
      if (EPI == 0) {
        uchar8 eq;
        #pragma unroll
        for (int j = 0; j < 8; ++j) {
          float fj = (j < 4) ? lo[j] : hi[j - 4];
          float bj = (j < 4) ? bias0[j] : bias1[j - 4];
          float hv = fj + bj;
          float a = hv > 0.f ? hv : expm1f(hv);
          ov[j] = (short)f2b(a);
          float e = hv > 0.f ? 1.f : (a + 1.f);   // elu'(h), in (0,1]
          eq[j] = (unsigned char)__float2int_rn(e * 255.f);
        }
        *(bf16x8*)(&OutB[idx]) = ov;
        *(uchar8*)(&Eout[idx]) = eq;
      } else {
        uchar8 ea = ea_pre[mf][p];
        #pragma unroll
        for (int j = 0; j < 8; ++j) {
          float fj = (j < 4) ? lo[j] : hi[j - 4];
          float e = (float)ea[j] * (1.f / 255.f);
          ov[j] = (short)f2b(fj * e);
        }
        *(bf16x8*)(&OutB[idx]) = ov;
      }
    }
  }
  #undef RD_A
  #undef RD_B
  #undef MFMA_H
  #undef PHASE
}

// ---------------- 128^2 GEMM, XCD-local grid + T2 XOR swizzle (R17 proven) ----------------
// Grid = dim3(M/128, N/128): XCD = row-block % 8 -> A panels L2-local.
// EPI 1: out_f32 = acc + bias[n] + Xadd[m,n]  (GEMM2)
// EPI 3 (GEMM4): out_bf16 = acc (skip if null) + fused Hutchinson partials into
//   sdg[(blockIdx.y*2 + wc)*M + row] (unique slot per wave -> no race, deterministic)
template<int EPI>
__global__ __launch_bounds__(256)
void gemm_bt(const bf16* __restrict__ A, const bf16* __restrict__ Bm,
             int M, int N, int K,
             bf16* __restrict__ OutB, float* __restrict__ OutF,
             const float* __restrict__ bias, const float* __restrict__ Xadd,
             const float* __restrict__ Vf, float* __restrict__ sdg, float coef) {
  __shared__ __align__(16) char pool[4 * 4352];   // As 8KB + Bs 8KB; epi scratch aliases
  bf16* As = (bf16*)pool;
  bf16* Bs = (bf16*)(pool + 8192);
  const int tid = threadIdx.x;
  const int l = tid & 63, w = tid >> 6;
  const int wr = w >> 1, wc = w & 1;
  const int lane16 = l & 15, lh = l >> 4;
  const int bm0 = blockIdx.x * 128, bn0 = blockIdx.y * 128;   // TRANSPOSED grid

  f32x4 acc[4][4] = {};
  const int nk = K >> 5;
  for (int kt = 0; kt < nk; ++kt) {
    const size_t kbase = (size_t)kt * 32;
    #pragma unroll
    for (int i = 0; i < 2; ++i) {
      int c = i * 256 + w * 64 + l;
      int row = c >> 2;
      int cbs = ((((c & 3) << 4) ^ ((row & 6) << 3)) >> 1);   // inverse-swizzled src
      const bf16* ga = A  + (size_t)(bm0 + row) * K + kbase + cbs;
      const bf16* gb = Bm + (size_t)(bn0 + row) * K + kbase + cbs;
      char* la = (char*)As + (size_t)(i * 256 + w * 64) * 16;
      char* lb = (char*)Bs + (size_t)(i * 256 + w * 64) * 16;
      load16_to_lds(ga, la);
      load16_to_lds(gb, lb);
    }
    __syncthreads();
    bf16x8 af[4], bfv[4];
    #pragma unroll
    for (int r = 0; r < 4; ++r) {
      int arow = wr * 64 + r * 16 + lane16;
      int aoff = (lh << 4) ^ ((arow & 6) << 3);   // swizzled byte offset in 64B row
      af[r] = *(const bf16x8*)((const char*)As + arow * 64 + aoff);
    }
    #pragma unroll
    for (int c = 0; c < 4; ++c) {
      int brow = wc * 64 + c * 16 + lane16;
      int boff = (lh << 4) ^ ((brow & 6) << 3);
      bfv[c] = *(const bf16x8*)((const char*)Bs + brow * 64 + boff);
    }
    #pragma unroll
    for (int r = 0; r < 4; ++r)
      #pragma unroll
      for (int c = 0; c < 4; ++c)
        acc[r][c] = __builtin_amdgcn_mfma_f32_16x16x32_bf16(af[r], bfv[c], acc[r][c], 0, 0, 0);
    __syncthreads();
  }

  if (EPI == 1) {
    #pragma unroll
    for (int r = 0; r < 4; ++r) {
      int gm_base = bm0 + wr * 64 + r * 16 + lh * 4;
      #pragma unroll
      for (int c = 0; c < 4; ++c) {
        int gn = bn0 + wc * 64 + c * 16 + lane16;
        #pragma unroll
        for (int q = 0; q < 4; ++q) {
          size_t idx = (size_t)(gm_base + q) * N + gn;
          OutF[idx] = acc[r][c][q] + bias[gn] + Xadd[idx];
        }
      }
    }
  } else {
    float* scr = (float*)(pool + w * 4352);
    float* sdgslot = sdg + (size_t)(blockIdx.y * 2 + wc) * M;   // private per (cb,wc)
    #pragma unroll
    for (int r = 0; r < 4; ++r) {
      #pragma unroll
      for (int c = 0; c < 4; ++c)
        #pragma unroll
        for (int q = 0; q < 4; ++q)
          scr[(lh * 4 + q) * 68 + c * 16 + lane16] = acc[r][c][q];
      #pragma unroll
      for (int p = 0; p < 2; ++p) {
        int row = p * 8 + (l >> 3);
        int c0 = (l & 7) * 8;
        const float* sp = &scr[row * 68 + c0];
        f32x4 lo = *(const f32x4*)sp;
        f32x4 hi = *(const f32x4*)(sp + 4);
        int gm = bm0 + wr * 64 + r * 16 + row;
        int gn = bn0 + wc * 64 + c0;
        size_t idx = (size_t)gm * N + gn;
        // fused Hutchinson partial: <w_row_block, v_row_block> in f32
        f32x4 v0 = *(const f32x4*)(Vf + idx);
        f32x4 v1 = *(const f32x4*)(Vf + idx + 4);
        float s = lo[0]*v0[0] + lo[1]*v0[1] + lo[2]*v0[2] + lo[3]*v0[3]
                + hi[0]*v1[0] + hi[1]*v1[1] + hi[2]*v1[2] + hi[3]*v1[3];
        s += __shfl_xor(s, 1); s += __shfl_xor(s, 2); s += __shfl_xor(s, 4);
        if ((l & 7) == 0) sdgslot[gm] += coef * s;   // unique slot per wave, no race
        if (OutB) {
          bf16x8 ov;
          #pragma unroll
          for (int j = 0; j < 8; ++j) {
            float fj = (j < 4) ? lo[j] : hi[j - 4];
            ov[j] = (short)f2b(fj);
          }
          *(bf16x8*)(&OutB[idx]) = ov;
        }
      }
      __syncthreads();
    }
  }
}

// ---------------- finalize: out[b] = ldz[b] + mean_s (sum_p sdgpart[s][p][b]) ----------------
__global__ void finalize(const float* __restrict__ ldz, const float* __restrict__ sdp,
                         float* __restrict__ out, int B, int S) {
  int b = blockIdx.x * 256 + threadIdx.x;
  if (b >= B) return;
  float acc = 0.f;
  for (int s = 0; s < S; ++s)
    for (int p = 0; p < 16; ++p)
      acc += sdp[((size_t)s * 16 + p) * B + b];
  out[b] = ldz[b] + acc / (float)S;
}

extern "C" void kernel_launch(void* const* d_in, const int* in_sizes, int n_in,
                              void* d_out, int out_size, void* d_ws, size_t ws_size,
                              hipStream_t stream) {
  const int B = 8192, D = 1024, H = 4096, S = 4, NPS = 8;
  const float* x   = (const float*)d_in[0];
  const float* ldz = (const float*)d_in[1];
  const float* W1  = (const float*)d_in[2];
  const float* b1  = (const float*)d_in[3];
  const float* W2  = (const float*)d_in[4];
  const float* b2  = (const float*)d_in[5];
  const float* v   = (const float*)d_in[6];
  float* z_out  = (float*)d_out;
  float* ld_out = z_out + (size_t)B * D;

  char* ws = (char*)d_ws;
  size_t off = 0;
  auto alloc = [&](size_t bytes) {
    char* p = ws + off; off = (off + bytes + 255) & ~(size_t)255; return p;
  };
  // Workspace ~194 MB (R16 proved >=240 MB usable)
  float* sdgpart = (float*)alloc((size_t)S * 16 * B * 4);     // 2 MB partial dots
  bf16* W1b  = (bf16*)alloc((size_t)D * H * 2);               // 8 MB  (B for GEMM4)
  bf16* W2b  = (bf16*)alloc((size_t)D * H * 2);               // 8 MB  (B for GEMM3)
  bf16* abuf = (bf16*)alloc((size_t)B * H * 2);               // 64 MB (a = elu(h))
  unsigned char* ebuf = (unsigned char*)alloc((size_t)B * H); // 32 MB (e quantized u8)
  bf16* wreg = (bf16*)alloc((size_t)B * D * 2);               // 16 MB (w state)
  bf16* treg = (bf16*)alloc((size_t)B * H * 2);               // 64 MB (t)
  // forward-only buffers alias INTO treg (dead before power series overwrites it):
  bf16* xb  = treg;                                            // 16 MB (x cast)
  bf16* W1T = (bf16*)((char*)treg + (size_t)16 * 1024 * 1024); // 8 MB
  bf16* W2T = (bf16*)((char*)treg + (size_t)24 * 1024 * 1024); // 8 MB
  (void)ws_size; (void)in_sizes; (void)n_in; (void)out_size;

  hipMemsetAsync(sdgpart, 0, (size_t)S * 16 * B * 4, stream);

  cast_f32_bf16<<<1024, 256, 0, stream>>>(x,  xb,  (size_t)B * D);
  cast_f32_bf16<<<1024, 256, 0, stream>>>(W1, W1b, (size_t)D * H);
  cast_f32_bf16<<<1024, 256, 0, stream>>>(W2, W2b, (size_t)D * H);
  transpose_cast<<<dim3(H / 32, D / 32), 256, 0, stream>>>(W1, W1T, D, H);
  transpose_cast<<<dim3(D / 32, H / 32), 256, 0, stream>>>(W2, W2T, H, D);

  // forward: a = elu(x@W1 + b1) (+ e stored u8);  z = x + a@W2 + b2
  gemm256<0><<<dim3(H / 256, B / 256), 512, 0, stream>>>(xb, W1T, B, H, D,
      abuf, b1, nullptr, ebuf);
  gemm_bt<1><<<dim3(B / 128, D / 128), 256, 0, stream>>>(abuf, W2T, B, D, H,
      nullptr, z_out, b2, x, nullptr, nullptr, 0.f);

  // power series, one sample at a time:
  //   t = (w@W2^T).*e ;  w <- t@W1^T with FUSED <w,v> partial accumulation
  for (int s = 0; s < S; ++s) {
    const float* vs = v + (size_t)s * B * D;
    cast_f32_bf16<<<1024, 256, 0, stream>>>(vs, wreg, (size_t)B * D);  // w_0 = v_s
    for (int k = 1; k <= NPS; ++k) {
      gemm256<2><<<dim3(H / 256, B / 256), 512, 0, stream>>>(wreg, W2b, B, H, D,
          treg, nullptr, ebuf, nullptr);
      float coef = ((k & 1) ? 1.f : -1.f) / (float)k;
      bf16* wout = (k < NPS) ? wreg : nullptr;   // last step's w never read again
      gemm_bt<3><<<dim3(B / 128, D / 128), 256, 0, stream>>>(treg, W1b, B, D, H,
          wout, nullptr, nullptr, nullptr, vs, sdgpart + (size_t)s * 16 * B, coef);
    }
  }
  finalize<<<B / 256, 256, 0, stream>>>(ldz, sdgpart, ld_out, B, S);
}

// Round 20
// 5790.362 us; speedup vs baseline: 1.0441x; 1.0056x over previous
//
#include <hip/hip_runtime.h>
#include <hip/hip_bf16.h>

using bf16 = __hip_bfloat16;
typedef __attribute__((ext_vector_type(8))) short bf16x8;   // 8 bf16 = 4 VGPRs (MFMA A/B frag)
typedef __attribute__((ext_vector_type(4))) float f32x4;    // MFMA C/D frag
typedef __attribute__((ext_vector_type(8))) unsigned char uchar8;

__device__ __forceinline__ float b2f(unsigned short u) {
  union { unsigned int i; float f; } x; x.i = ((unsigned int)u) << 16; return x.f;
}
__device__ __forceinline__ unsigned short f2b(float f) {
  __hip_bfloat16 h = __float2bfloat16(f);
  return *reinterpret_cast<unsigned short*>(&h);
}

__device__ __forceinline__ void load16_to_lds(const bf16* g, void* lds) {
  __builtin_amdgcn_global_load_lds((const __attribute__((address_space(1))) void*)g,
                                   (__attribute__((address_space(3))) void*)lds, 16, 0, 0);
}

#define FENCE() asm volatile("" ::: "memory")
#define BAR() do { FENCE(); __builtin_amdgcn_s_barrier(); FENCE(); } while (0)
#define SCHED_PIN() __builtin_amdgcn_sched_barrier(0)

// ---------------- elementwise cast f32 -> bf16 ----------------
__global__ void cast_f32_bf16(const float* __restrict__ in, bf16* __restrict__ out, size_t n) {
  size_t i0 = ((size_t)blockIdx.x * 256 + threadIdx.x) * 4;
  size_t stride = (size_t)gridDim.x * 256 * 4;
  for (size_t i = i0; i < n; i += stride) {
    float4 f = *(const float4*)(in + i);
    ushort4 o;
    o.x = f2b(f.x); o.y = f2b(f.y); o.z = f2b(f.z); o.w = f2b(f.w);
    *(ushort4*)(out + i) = o;
  }
}

// ---------------- transpose + cast: in [R][C] f32 -> out [C][R] bf16 ----------------
__global__ void transpose_cast(const float* __restrict__ in, bf16* __restrict__ out, int R, int C) {
  __shared__ float tile[32][33];
  int tx = threadIdx.x & 31, ty = threadIdx.x >> 5;  // 32 x 8
  int r0 = blockIdx.y * 32, c0 = blockIdx.x * 32;
  #pragma unroll
  for (int i = 0; i < 32; i += 8)
    tile[ty + i][tx] = in[(size_t)(r0 + ty + i) * C + (c0 + tx)];
  __syncthreads();
  #pragma unroll
  for (int i = 0; i < 32; i += 8)
    out[(size_t)(c0 + ty + i) * R + (r0 + tx)] = __float2bfloat16(tile[tx][ty + i]);
}

// ============ 256x256 8-phase GEMM (T2+T3+T4+T5 + sched-pin): C = A[M,K]*B^T ============
// B stored [N][K] row-major. BK=64, 512 threads = 8 waves (2M x 4N), LDS 128KB 2-buf.
// EPI 0: out = elu(acc + bias[n]); ALSO store e=elu'(h) quantized u8 to Eout (for GEMM3)
// EPI 2: out = acc * e, e = Ea_u8[m,n] / 255   (u8 halves the Ea stream: 64->32 MB)
template<int EPI>
__global__ __launch_bounds__(512, 2)
void gemm256(const bf16* __restrict__ A, const bf16* __restrict__ Bm,
             int M, int N, int K,
             bf16* __restrict__ OutB,
             const float* __restrict__ bias,
             const unsigned char* __restrict__ Ea,
             unsigned char* __restrict__ Eout) {
  __shared__ __align__(16) char pool[131072];
  char* Albs = pool;           // A tiles [2buf][256 rows][128B], XOR-swizzled
  char* Blbs = pool + 65536;   // B tiles, same layout
  const int tid = threadIdx.x;
  const int l = tid & 63, w = tid >> 6;
  const int lane16 = l & 15, lh = l >> 4;
  const int wr = w >> 2, wc = w & 3;            // wave grid 2(M) x 4(N)
  const int bm0 = blockIdx.y * 256, bn0 = blockIdx.x * 256;
  const int NT2 = K >> 7;

  auto stage = [&](const bf16* G, int grow0, int kbase, char* ldsbase) {
    #pragma unroll
    for (int r = 0; r < 2; ++r) {
      int p = (r * 512 + tid) * 16;
      int row = p >> 7, colb = p & 127;
      int cs = colb ^ ((row & 7) << 4);
      const bf16* g = G + (size_t)(grow0 + row) * K + kbase + (cs >> 1);
      load16_to_lds(g, ldsbase + (size_t)(r * 512 + w * 64) * 16);  // wave-uniform base
    }
  };
  auto rd = [&](const char* base, int row, int colb) -> bf16x8 {
    return *(const bf16x8*)(base + row * 128 + (colb ^ ((row & 7) << 4)));
  };

  f32x4 acc[8][4] = {};
  bf16x8 a_r[4][2], b_r[4][2];

  #define RD_A(mq, buf) { _Pragma("unroll") for (int i = 0; i < 4; ++i) \
      _Pragma("unroll") for (int kk = 0; kk < 2; ++kk) \
      a_r[i][kk] = rd(Albs + (buf) * 32768, wr * 128 + (mq) * 64 + i * 16 + lane16, kk * 64 + lh * 16); }
  #define RD_B(buf) { _Pragma("unroll") for (int nf = 0; nf < 4; ++nf) \
      _Pragma("unroll") for (int kk = 0; kk < 2; ++kk) \
      b_r[nf][kk] = rd(Blbs + (buf) * 32768, wc * 64 + nf * 16 + lane16, kk * 64 + lh * 16); }
  #define MFMA_H(mq, n0) { __builtin_amdgcn_s_setprio(1); \
      _Pragma("unroll") for (int i = 0; i < 4; ++i) \
      _Pragma("unroll") for (int nn = 0; nn < 2; ++nn) \
      _Pragma("unroll") for (int kk = 0; kk < 2; ++kk) \
        acc[(mq)*4+i][(n0)+nn] = __builtin_amdgcn_mfma_f32_16x16x32_bf16( \
            a_r[i][kk], b_r[(n0)+nn][kk], acc[(mq)*4+i][(n0)+nn], 0, 0, 0); \
      __builtin_amdgcn_s_setprio(0); }
  #define PHASE(BODY_PRE, MFMA_CALL) { BODY_PRE; BAR(); SCHED_PIN(); MFMA_CALL; SCHED_PIN(); BAR(); }

  // prologue: buf0 {B0,B1,A0,A1} (ktile 0); buf1 {B0,B1,A0} (ktile 1). 7 halves = 14 loads.
  stage(Bm, bn0 + 0,   0,  Blbs + 0);
  stage(Bm, bn0 + 128, 0,  Blbs + 16384);
  stage(A,  bm0 + 0,   0,  Albs + 0);
  stage(A,  bm0 + 128, 0,  Albs + 16384);
  stage(Bm, bn0 + 0,   64, Blbs + 32768);
  stage(Bm, bn0 + 128, 64, Blbs + 32768 + 16384);
  stage(A,  bm0 + 0,   64, Albs + 32768);
  asm volatile("s_waitcnt vmcnt(6)" ::: "memory");  // buf0's 4 halves landed
  SCHED_PIN();
  BAR();

  for (int t = 0; t < NT2; ++t) {
    const int k2 = (2 * t + 2) * 64, k3 = (2 * t + 3) * 64;
    const bool nl = (t < NT2 - 1);
    PHASE({ RD_B(0); RD_A(0, 0); stage(A, bm0 + 128, (2 * t + 1) * 64, Albs + 32768 + 16384); },
          MFMA_H(0, 0));
    PHASE({ if (nl) stage(Bm, bn0 + 0, k2, Blbs + 0); }, MFMA_H(0, 2));
    PHASE({ RD_A(1, 0); if (nl) stage(Bm, bn0 + 128, k2, Blbs + 16384); }, MFMA_H(1, 0));
    { if (nl) stage(A, bm0 + 0, k2, Albs + 0);
      BAR(); SCHED_PIN(); MFMA_H(1, 2); SCHED_PIN();
      if (nl) { asm volatile("s_waitcnt vmcnt(6)" ::: "memory"); }
      else    { asm volatile("s_waitcnt vmcnt(0)" ::: "memory"); }
      SCHED_PIN(); BAR(); }
    PHASE({ RD_B(1); RD_A(0, 1); if (nl) stage(A, bm0 + 128, k2, Albs + 16384); },
          MFMA_H(0, 0));
    PHASE({ if (nl) stage(Bm, bn0 + 0, k3, Blbs + 32768); }, MFMA_H(0, 2));
    PHASE({ RD_A(1, 1); if (nl) stage(Bm, bn0 + 128, k3, Blbs + 32768 + 16384); }, MFMA_H(1, 0));
    { if (nl) stage(A, bm0 + 0, k3, Albs + 32768);
      BAR(); SCHED_PIN(); MFMA_H(1, 2); SCHED_PIN();
      if (nl) { asm volatile("s_waitcnt vmcnt(6)" ::: "memory"); }
      SCHED_PIN(); BAR(); }
  }

  // ---- epilogue: per-wave repack (scratch aliases dead pool), 16B bf16x8 stores
  float* scr = (float*)(pool + w * 4352);   // per-wave 16x68 f32
  const int row0 = bm0 + wr * 128, col0 = bn0 + wc * 64;
  const int erow = l >> 3, ecol = (l & 7) * 8;
  f32x4 bias0 = {}, bias1 = {};
  uchar8 ea_pre[8][2];
  if (EPI == 0) {
    bias0 = *(const f32x4*)&bias[col0 + ecol];
    bias1 = *(const f32x4*)&bias[col0 + ecol + 4];
  } else {
    #pragma unroll
    for (int mf = 0; mf < 8; ++mf)
      #pragma unroll
      for (int p = 0; p < 2; ++p) {
        int gm = row0 + mf * 16 + p * 8 + erow;
        ea_pre[mf][p] = *(const uchar8*)&Ea[(size_t)gm * N + col0 + ecol];
      }
  }
  SCHED_PIN();
  #pragma unroll
  for (int mf = 0; mf < 8; ++mf) {
    #pragma unroll
    for (int nf = 0; nf < 4; ++nf)
      #pragma unroll
      for (int q = 0; q < 4; ++q)
        scr[(lh * 4 + q) * 68 + nf * 16 + lane16] = acc[mf][nf][q];
    #pragma unroll
    for (int p = 0; p < 2; ++p) {
      int row = p * 8 + erow;
      const float* sp = &scr[row * 68 + ecol];
      f32x4 lo = *(const f32x4*)sp;
      f32x4 hi = *(const f32x4*)(sp + 4);
      int gm = row0 + mf * 16 + row;
      size_t idx = (size_t)gm * N + col0 + ecol;
      bf16x8 ov;
      if (EPI == 0) {
        uchar8 eq;
        #pragma unroll
        for (int j = 0; j < 8; ++j) {
          float fj = (j < 4) ? lo[j] : hi[j - 4];
          float bj = (j < 4) ? bias0[j] : bias1[j - 4];
          float hv = fj + bj;
          float a = hv > 0.f ? hv : expm1f(hv);
          ov[j] = (short)f2b(a);
          float e = hv > 0.f ? 1.f : (a + 1.f);   // elu'(h), in (0,1]
          eq[j] = (unsigned char)__float2int_rn(e * 255.f);
        }
        *(bf16x8*)(&OutB[idx]) = ov;
        *(uchar8*)(&Eout[idx]) = eq;
      } else {
        uchar8 ea = ea_pre[mf][p];
        #pragma unroll
        for (int j = 0; j < 8; ++j) {
          float fj = (j < 4) ? lo[j] : hi[j - 4];
          float e = (float)ea[j] * (1.f / 255.f);
          ov[j] = (short)f2b(fj * e);
        }
        *(bf16x8*)(&OutB[idx]) = ov;
      }
    }
  }
  #undef RD_A
  #undef RD_B
  #undef MFMA_H
  #undef PHASE
}

// ---------------- 128^2 GEMM, XCD-local grid + T2 XOR swizzle (R17 proven) ----------------
// Grid = dim3(M/128, N/128): XCD = row-block % 8 -> A panels L2-local.
// EPI 1: out_f32 = acc + bias[n] + Xadd[m,n]  (GEMM2)
// EPI 3 (GEMM4): out_bf16 = acc (skip if null) + fused Hutchinson partials vs bf16 Vb:
//   sdg[(blockIdx.y*2 + wc)*M + row] (unique slot per wave -> no race, deterministic)
template<int EPI>
__global__ __launch_bounds__(256)
void gemm_bt(const bf16* __restrict__ A, const bf16* __restrict__ Bm,
             int M, int N, int K,
             bf16* __restrict__ OutB, float* __restrict__ OutF,
             const float* __restrict__ bias, const float* __restrict__ Xadd,
             const bf16* __restrict__ Vb, float* __restrict__ sdg, float coef) {
  __shared__ __align__(16) char pool[4 * 4352];   // As 8KB + Bs 8KB; epi scratch aliases
  bf16* As = (bf16*)pool;
  bf16* Bs = (bf16*)(pool + 8192);
  const int tid = threadIdx.x;
  const int l = tid & 63, w = tid >> 6;
  const int wr = w >> 1, wc = w & 1;
  const int lane16 = l & 15, lh = l >> 4;
  const int bm0 = blockIdx.x * 128, bn0 = blockIdx.y * 128;   // TRANSPOSED grid

  f32x4 acc[4][4] = {};
  const int nk = K >> 5;
  for (int kt = 0; kt < nk; ++kt) {
    const size_t kbase = (size_t)kt * 32;
    #pragma unroll
    for (int i = 0; i < 2; ++i) {
      int c = i * 256 + w * 64 + l;
      int row = c >> 2;
      int cbs = ((((c & 3) << 4) ^ ((row & 6) << 3)) >> 1);   // inverse-swizzled src
      const bf16* ga = A  + (size_t)(bm0 + row) * K + kbase + cbs;
      const bf16* gb = Bm + (size_t)(bn0 + row) * K + kbase + cbs;
      char* la = (char*)As + (size_t)(i * 256 + w * 64) * 16;
      char* lb = (char*)Bs + (size_t)(i * 256 + w * 64) * 16;
      load16_to_lds(ga, la);
      load16_to_lds(gb, lb);
    }
    __syncthreads();
    bf16x8 af[4], bfv[4];
    #pragma unroll
    for (int r = 0; r < 4; ++r) {
      int arow = wr * 64 + r * 16 + lane16;
      int aoff = (lh << 4) ^ ((arow & 6) << 3);   // swizzled byte offset in 64B row
      af[r] = *(const bf16x8*)((const char*)As + arow * 64 + aoff);
    }
    #pragma unroll
    for (int c = 0; c < 4; ++c) {
      int brow = wc * 64 + c * 16 + lane16;
      int boff = (lh << 4) ^ ((brow & 6) << 3);
      bfv[c] = *(const bf16x8*)((const char*)Bs + brow * 64 + boff);
    }
    #pragma unroll
    for (int r = 0; r < 4; ++r)
      #pragma unroll
      for (int c = 0; c < 4; ++c)
        acc[r][c] = __builtin_amdgcn_mfma_f32_16x16x32_bf16(af[r], bfv[c], acc[r][c], 0, 0, 0);
    __syncthreads();
  }

  if (EPI == 1) {
    #pragma unroll
    for (int r = 0; r < 4; ++r) {
      int gm_base = bm0 + wr * 64 + r * 16 + lh * 4;
      #pragma unroll
      for (int c = 0; c < 4; ++c) {
        int gn = bn0 + wc * 64 + c * 16 + lane16;
        #pragma unroll
        for (int q = 0; q < 4; ++q) {
          size_t idx = (size_t)(gm_base + q) * N + gn;
          OutF[idx] = acc[r][c][q] + bias[gn] + Xadd[idx];
        }
      }
    }
  } else {
    float* scr = (float*)(pool + w * 4352);
    float* sdgslot = sdg + (size_t)(blockIdx.y * 2 + wc) * M;   // private per (cb,wc)
    #pragma unroll
    for (int r = 0; r < 4; ++r) {
      #pragma unroll
      for (int c = 0; c < 4; ++c)
        #pragma unroll
        for (int q = 0; q < 4; ++q)
          scr[(lh * 4 + q) * 68 + c * 16 + lane16] = acc[r][c][q];
      #pragma unroll
      for (int p = 0; p < 2; ++p) {
        int row = p * 8 + (l >> 3);
        int c0 = (l & 7) * 8;
        const float* sp = &scr[row * 68 + c0];
        f32x4 lo = *(const f32x4*)sp;
        f32x4 hi = *(const f32x4*)(sp + 4);
        int gm = bm0 + wr * 64 + r * 16 + row;
        int gn = bn0 + wc * 64 + c0;
        size_t idx = (size_t)gm * N + gn;
        // fused Hutchinson partial: <w_row_block, v_row_block>, v in bf16 (16B not 32B)
        bf16x8 vv = *(const bf16x8*)(Vb + idx);
        float s = lo[0]*b2f((unsigned short)vv[0]) + lo[1]*b2f((unsigned short)vv[1])
                + lo[2]*b2f((unsigned short)vv[2]) + lo[3]*b2f((unsigned short)vv[3])
                + hi[0]*b2f((unsigned short)vv[4]) + hi[1]*b2f((unsigned short)vv[5])
                + hi[2]*b2f((unsigned short)vv[6]) + hi[3]*b2f((unsigned short)vv[7]);
        s += __shfl_xor(s, 1); s += __shfl_xor(s, 2); s += __shfl_xor(s, 4);
        if ((l & 7) == 0) sdgslot[gm] += coef * s;   // unique slot per wave, no race
        if (OutB) {
          bf16x8 ov;
          #pragma unroll
          for (int j = 0; j < 8; ++j) {
            float fj = (j < 4) ? lo[j] : hi[j - 4];
            ov[j] = (short)f2b(fj);
          }
          *(bf16x8*)(&OutB[idx]) = ov;
        }
      }
      __syncthreads();
    }
  }
}

// ---------------- finalize: out[b] = ldz[b] + mean_s (sum_p sdgpart[s][p][b]) ----------------
__global__ void finalize(const float* __restrict__ ldz, const float* __restrict__ sdp,
                         float* __restrict__ out, int B, int S) {
  int b = blockIdx.x * 256 + threadIdx.x;
  if (b >= B) return;
  float acc = 0.f;
  for (int s = 0; s < S; ++s)
    for (int p = 0; p < 16; ++p)
      acc += sdp[((size_t)s * 16 + p) * B + b];
  out[b] = ldz[b] + acc / (float)S;
}

extern "C" void kernel_launch(void* const* d_in, const int* in_sizes, int n_in,
                              void* d_out, int out_size, void* d_ws, size_t ws_size,
                              hipStream_t stream) {
  const int B = 8192, D = 1024, H = 4096, S = 4, NPS = 8;
  const float* x   = (const float*)d_in[0];
  const float* ldz = (const float*)d_in[1];
  const float* W1  = (const float*)d_in[2];
  const float* b1  = (const float*)d_in[3];
  const float* W2  = (const float*)d_in[4];
  const float* b2  = (const float*)d_in[5];
  const float* v   = (const float*)d_in[6];
  float* z_out  = (float*)d_out;
  float* ld_out = z_out + (size_t)B * D;

  char* ws = (char*)d_ws;
  size_t off = 0;
  auto alloc = [&](size_t bytes) {
    char* p = ws + off; off = (off + bytes + 255) & ~(size_t)255; return p;
  };
  // Workspace ~210 MB (R16 proved >=240 MB usable)
  float* sdgpart = (float*)alloc((size_t)S * 16 * B * 4);     // 2 MB partial dots
  bf16* W1b  = (bf16*)alloc((size_t)D * H * 2);               // 8 MB  (B for GEMM4)
  bf16* W2b  = (bf16*)alloc((size_t)D * H * 2);               // 8 MB  (B for GEMM3)
  bf16* abuf = (bf16*)alloc((size_t)B * H * 2);               // 64 MB (a = elu(h))
  unsigned char* ebuf = (unsigned char*)alloc((size_t)B * H); // 32 MB (e quantized u8)
  bf16* wreg = (bf16*)alloc((size_t)B * D * 2);               // 16 MB (w state)
  bf16* vbuf = (bf16*)alloc((size_t)B * D * 2);               // 16 MB (v_s cast, probe)
  bf16* treg = (bf16*)alloc((size_t)B * H * 2);               // 64 MB (t)
  // forward-only buffers alias INTO treg (dead before power series overwrites it):
  bf16* xb  = treg;                                            // 16 MB (x cast)
  bf16* W1T = (bf16*)((char*)treg + (size_t)16 * 1024 * 1024); // 8 MB
  bf16* W2T = (bf16*)((char*)treg + (size_t)24 * 1024 * 1024); // 8 MB
  (void)ws_size; (void)in_sizes; (void)n_in; (void)out_size;

  hipMemsetAsync(sdgpart, 0, (size_t)S * 16 * B * 4, stream);

  cast_f32_bf16<<<1024, 256, 0, stream>>>(x,  xb,  (size_t)B * D);
  cast_f32_bf16<<<1024, 256, 0, stream>>>(W1, W1b, (size_t)D * H);
  cast_f32_bf16<<<1024, 256, 0, stream>>>(W2, W2b, (size_t)D * H);
  transpose_cast<<<dim3(H / 32, D / 32), 256, 0, stream>>>(W1, W1T, D, H);
  transpose_cast<<<dim3(D / 32, H / 32), 256, 0, stream>>>(W2, W2T, H, D);

  // forward: a = elu(x@W1 + b1) (+ e stored u8);  z = x + a@W2 + b2
  gemm256<0><<<dim3(H / 256, B / 256), 512, 0, stream>>>(xb, W1T, B, H, D,
      abuf, b1, nullptr, ebuf);
  gemm_bt<1><<<dim3(B / 128, D / 128), 256, 0, stream>>>(abuf, W2T, B, D, H,
      nullptr, z_out, b2, x, nullptr, nullptr, 0.f);

  // power series, one sample at a time:
  //   t = (w@W2^T).*e ;  w <- t@W1^T with FUSED <w,v> partial accumulation (v bf16)
  for (int s = 0; s < S; ++s) {
    const float* vs = v + (size_t)s * B * D;
    cast_f32_bf16<<<1024, 256, 0, stream>>>(vs, vbuf, (size_t)B * D);  // v_s -> bf16 once
    for (int k = 1; k <= NPS; ++k) {
      const bf16* wsrc = (k == 1) ? vbuf : wreg;     // w_0 = v_s (no extra copy)
      gemm256<2><<<dim3(H / 256, B / 256), 512, 0, stream>>>(wsrc, W2b, B, H, D,
          treg, nullptr, ebuf, nullptr);
      float coef = ((k & 1) ? 1.f : -1.f) / (float)k;
      bf16* wout = (k < NPS) ? wreg : nullptr;       // last step's w never read again
      gemm_bt<3><<<dim3(B / 128, D / 128), 256, 0, stream>>>(treg, W1b, B, D, H,
          wout, nullptr, nullptr, nullptr, vbuf, sdgpart + (size_t)s * 16 * B, coef);
    }
  }
  finalize<<<B / 256, 256, 0, stream>>>(ldz, sdgpart, ld_out, B, S);
}